// Round 1
// baseline (9884.225 us; speedup 1.0000x reference)
//
#include <hip/hip_runtime.h>
#include <hip/hip_cooperative_groups.h>

namespace cg = cooperative_groups;

#define BB 8
#define NN 2048
#define WGS 1024
#define GRID 256
#define WG_PER_B (GRID / BB)              // 32 WGs per batch
#define ROWS_PER_WG (NN / WG_PER_B)       // 64
#define NWAVES (WGS / 64)                 // 16
#define ROWS_PER_WAVE (ROWS_PER_WG / NWAVES) // 4
#define CHUNKS (NN / 64)                  // 32
#define MAX_ITER 50

// eps = 0.005; work in log2 domain: SCL = log2(e)/eps
constexpr float SCL      = 288.5390081777927f;
constexpr float LN2f     = 0.6931471805599453f;
constexpr float EPSf     = 0.005f;
constexpr float EPS_LOGMU = -0.03812309493079699f; // 0.005 * (-ln 2048)

__device__ __forceinline__ float wmax(float v) {
  #pragma unroll
  for (int d = 32; d; d >>= 1) v = fmaxf(v, __shfl_xor(v, d, 64));
  return v;
}
__device__ __forceinline__ float wsum(float v) {
  #pragma unroll
  for (int d = 32; d; d >>= 1) v += __shfl_xor(v, d, 64);
  return v;
}

// One wave computes one output potential row: logsumexp over 2048 entries of JA.
// JA[j] = {x_j, y_j, z_j, A_j} with A_j = (pot_j - |q_j|^2) * SCL  (log2 units)
// T_ij = A_j + (2s p_i)·q_j ;  full exponent = T_ij + Bi, Bi = -|p_i|^2 s (row const)
__device__ __forceinline__ void potentialRows(
    const float4* __restrict__ JA, const float4* __restrict__ JOwn,
    float* __restrict__ outPot, int rowbase, int wv, int lane)
{
  #pragma unroll 1
  for (int r = 0; r < ROWS_PER_WAVE; ++r) {
    const int i = rowbase + wv * ROWS_PER_WAVE + r;
    float4 pi = JOwn[i];                       // broadcast LDS read
    float pp = fmaf(pi.x, pi.x, fmaf(pi.y, pi.y, pi.z * pi.z));
    float Xx = 2.f * SCL * pi.x, Xy = 2.f * SCL * pi.y, Xz = 2.f * SCL * pi.z;
    float Bi = -pp * SCL;
    float t[CHUNKS];
    float m4[4] = {-3.4e38f, -3.4e38f, -3.4e38f, -3.4e38f};
    #pragma unroll
    for (int k = 0; k < CHUNKS; ++k) {
      float4 q = JA[k * 64 + lane];
      float T = fmaf(Xx, q.x, fmaf(Xy, q.y, fmaf(Xz, q.z, q.w)));
      t[k] = T;
      m4[k & 3] = fmaxf(m4[k & 3], T);
    }
    float m = wmax(fmaxf(fmaxf(m4[0], m4[1]), fmaxf(m4[2], m4[3])));
    float s4[4] = {0.f, 0.f, 0.f, 0.f};
    #pragma unroll
    for (int k = 0; k < CHUNKS; ++k) s4[k & 3] += exp2f(t[k] - m);
    float ssum = wsum((s4[0] + s4[1]) + (s4[2] + s4[3]));
    float lse = Bi + m + log2f(ssum);          // log2 logsumexp (incl. row const)
    float pot = EPS_LOGMU - EPSf * LN2f * lse; // back to natural units
    if (lane == 0) outPot[i] = pot;
  }
}

__global__ __launch_bounds__(WGS, 4) void emd_sinkhorn(
    const float* __restrict__ pcs1, const float* __restrict__ pcs2,
    float* __restrict__ out, float* __restrict__ fArr,
    float* __restrict__ gArr, float* __restrict__ accum)
{
  cg::grid_group grid = cg::this_grid();
  __shared__ float4 J1[NN];   // pcs1 coords, .w = (f_i - pp_i)*SCL when staged
  __shared__ float4 J2[NN];   // pcs2 coords, .w = (g_j - qq_j)*SCL when staged
  __shared__ float redbuf[NWAVES];

  const int wg = blockIdx.x, tid = threadIdx.x;
  const int b = wg / WG_PER_B, sub = wg % WG_PER_B;
  const int rowbase = sub * ROWS_PER_WG;
  const int lane = tid & 63, wv = tid >> 6;

  const float* p1 = pcs1 + (size_t)b * NN * 3;
  const float* p2 = pcs2 + (size_t)b * NN * 3;
  float* myF = fArr + b * NN;
  float* myG = gArr + b * NN;

  // load this batch's coordinates into LDS (persistent for whole kernel)
  for (int i = tid; i < NN; i += WGS) {
    J1[i] = make_float4(p1[3 * i], p1[3 * i + 1], p1[3 * i + 2], 0.f);
    J2[i] = make_float4(p2[3 * i], p2[3 * i + 1], p2[3 * i + 2], 0.f);
  }
  if (wg == 0 && tid == 0) *accum = 0.f;
  __syncthreads();

  for (int it = 0; it < MAX_ITER; ++it) {
    // ---- f-update: stage A_j from g (g=0 at it==0)
    for (int j = tid; j < NN; j += WGS) {
      float4 q = J2[j];
      float qq = fmaf(q.x, q.x, fmaf(q.y, q.y, q.z * q.z));
      float gj = (it == 0) ? 0.f : myG[j];
      J2[j].w = (gj - qq) * SCL;
    }
    __syncthreads();
    potentialRows(J2, J1, myF, rowbase, wv, lane);
    grid.sync();                               // f complete, batch-wide

    // ---- g-update: stage A_i from fresh f
    for (int i = tid; i < NN; i += WGS) {
      float4 p = J1[i];
      float pp = fmaf(p.x, p.x, fmaf(p.y, p.y, p.z * p.z));
      J1[i].w = (myF[i] - pp) * SCL;
    }
    __syncthreads();
    potentialRows(J1, J2, myG, rowbase, wv, lane);
    grid.sync();                               // g complete
  }

  // ---- final: dist_i = N * sum_j exp((f_i+g_j-C_ij)/eps) * C_ij
  for (int j = tid; j < NN; j += WGS) J2[j].w = myG[j] * SCL;
  __syncthreads();

  float part = 0.f;
  #pragma unroll 1
  for (int r = 0; r < ROWS_PER_WAVE; ++r) {
    const int i = rowbase + wv * ROWS_PER_WAVE + r;
    float4 pi = J1[i];
    float Fi = myF[i] * SCL;
    float a4[4] = {0.f, 0.f, 0.f, 0.f};
    #pragma unroll
    for (int k = 0; k < CHUNKS; ++k) {
      float4 q = J2[k * 64 + lane];
      float dx = pi.x - q.x, dy = pi.y - q.y, dz = pi.z - q.z;
      float c = fmaf(dx, dx, fmaf(dy, dy, dz * dz));
      float U = fmaf(-SCL, c, Fi + q.w);       // log2 P_ij
      float p = exp2f(U);
      a4[k & 3] = fmaf(p, c, a4[k & 3]);
    }
    float lacc = wsum((a4[0] + a4[1]) + (a4[2] + a4[3]));
    float dist = (float)NN * lacc;
    if (lane == 0) part += sqrtf(dist + 1e-12f);
  }
  if (lane == 0) redbuf[wv] = part;
  __syncthreads();
  if (tid == 0) {
    float s = 0.f;
    #pragma unroll
    for (int w = 0; w < NWAVES; ++w) s += redbuf[w];
    atomicAdd(accum, s);
  }
  grid.sync();
  if (wg == 0 && tid == 0) out[0] = atomicAdd(accum, 0.f) * (1.f / 16384.f);
}

extern "C" void kernel_launch(void* const* d_in, const int* in_sizes, int n_in,
                              void* d_out, int out_size, void* d_ws, size_t ws_size,
                              hipStream_t stream) {
  const float* pcs1 = (const float*)d_in[0];
  const float* pcs2 = (const float*)d_in[1];
  float* out  = (float*)d_out;
  float* ws   = (float*)d_ws;
  float* fArr = ws;                 // BB*NN floats
  float* gArr = ws + BB * NN;       // BB*NN floats
  float* acc  = ws + 2 * BB * NN;   // 1 float
  void* args[] = { &pcs1, &pcs2, &out, &fArr, &gArr, &acc };
  hipLaunchCooperativeKernel(reinterpret_cast<void*>(emd_sinkhorn),
                             dim3(GRID), dim3(WGS), args, 0, stream);
}